// Round 3
// baseline (581.560 us; speedup 1.0000x reference)
//
#include <hip/hip_runtime.h>
#include <hip/hip_bf16.h>

typedef __attribute__((ext_vector_type(4))) float f32x4;
typedef __attribute__((ext_vector_type(8))) short s16x8;
typedef __attribute__((ext_vector_type(4))) short s16x4;

#define DEV __device__ __forceinline__

DEV unsigned short f2bf(float f) {
  union { float f; unsigned u; } v; v.f = f;
  unsigned r = v.u + 0x7FFFu + ((v.u >> 16) & 1u);
  return (unsigned short)(r >> 16);
}

// ---------------- fused QKV projection: Y = X * W^T + b (bf16 out) ----------------
__global__ __launch_bounds__(256) void proj_kernel(
    const float* __restrict__ Qx, const float* __restrict__ Kx, const float* __restrict__ Vx,
    const float* __restrict__ Wq, const float* __restrict__ bq,
    const float* __restrict__ Wk, const float* __restrict__ bk,
    const float* __restrict__ Wv, const float* __restrict__ bv,
    unsigned short* __restrict__ qb, unsigned short* __restrict__ kb,
    unsigned short* __restrict__ vt)
{
  const int z = blockIdx.z;
  const float* X = (z == 0) ? Qx : (z == 1) ? Kx : Vx;
  const float* W = (z == 0) ? Wq : (z == 1) ? Wk : Wv;
  const float* B = (z == 0) ? bq : (z == 1) ? bk : bv;
  unsigned short* Y = (z == 0) ? qb : (z == 1) ? kb : vt;
  const int out_mode = (z == 2);

  const int row0 = blockIdx.x * 128;
  const int col0 = blockIdx.y * 128;
  const int tid  = threadIdx.x;
  const int lane = tid & 63;
  const int w    = tid >> 6;
  const int wr = w >> 1, wc = w & 1;
  const int l15 = lane & 15, lg = lane >> 4;

  __shared__ unsigned short As[128][40];
  __shared__ unsigned short Bs[128][40];

  f32x4 acc[4][4];
  #pragma unroll
  for (int i = 0; i < 4; ++i)
    #pragma unroll
    for (int j = 0; j < 4; ++j) acc[i][j] = {0.f, 0.f, 0.f, 0.f};

  const int lr = tid >> 3;
  const int lc = (tid & 7) << 2;

  for (int k0 = 0; k0 < 256; k0 += 32) {
    __syncthreads();
    #pragma unroll
    for (int p = 0; p < 4; ++p) {
      const int r = p * 32 + lr;
      f32x4 a = *reinterpret_cast<const f32x4*>(&X[(size_t)(row0 + r) * 256 + k0 + lc]);
      s16x4 ha;
      ha[0] = (short)f2bf(a[0]); ha[1] = (short)f2bf(a[1]);
      ha[2] = (short)f2bf(a[2]); ha[3] = (short)f2bf(a[3]);
      *reinterpret_cast<s16x4*>(&As[r][lc]) = ha;
      f32x4 b = *reinterpret_cast<const f32x4*>(&W[(size_t)(col0 + r) * 256 + k0 + lc]);
      s16x4 hb;
      hb[0] = (short)f2bf(b[0]); hb[1] = (short)f2bf(b[1]);
      hb[2] = (short)f2bf(b[2]); hb[3] = (short)f2bf(b[3]);
      *reinterpret_cast<s16x4*>(&Bs[r][lc]) = hb;
    }
    __syncthreads();
    s16x8 af[4], bf[4];
    #pragma unroll
    for (int mi = 0; mi < 4; ++mi)
      af[mi] = *reinterpret_cast<const s16x8*>(&As[wr * 64 + mi * 16 + l15][lg * 8]);
    #pragma unroll
    for (int ni = 0; ni < 4; ++ni)
      bf[ni] = *reinterpret_cast<const s16x8*>(&Bs[wc * 64 + ni * 16 + l15][lg * 8]);
    #pragma unroll
    for (int mi = 0; mi < 4; ++mi)
      #pragma unroll
      for (int ni = 0; ni < 4; ++ni)
        acc[mi][ni] = __builtin_amdgcn_mfma_f32_16x16x32_bf16(af[mi], bf[ni], acc[mi][ni], 0, 0, 0);
  }

  #pragma unroll
  for (int ni = 0; ni < 4; ++ni) {
    const int col = col0 + wc * 64 + ni * 16 + l15;
    const float bv_ = B[col];
    #pragma unroll
    for (int mi = 0; mi < 4; ++mi)
      #pragma unroll
      for (int j = 0; j < 4; ++j) {
        const int row = row0 + wr * 64 + mi * 16 + lg * 4 + j;
        const unsigned short h = f2bf(acc[mi][ni][j] + bv_);
        if (out_mode == 0) Y[(size_t)row * 256 + col] = h;
        else Y[((size_t)((row >> 12) * 256 + col)) * 4096 + (row & 4095)] = h;
      }
  }
}

// ---------------- flash attention ----------------
// 8 waves = 4 q-groups (32 q each -> 128 q-span) x 2 T-parities (in-block).
// TS-way T-split across blocks; unnormalized partials (O', m, L) to ws; merge kernel finishes.
__global__ __launch_bounds__(512, 2) void attn_kernel(
    const unsigned short* __restrict__ Qb,
    const unsigned short* __restrict__ Kb,
    const unsigned short* __restrict__ Vt,
    float* __restrict__ pO, float* __restrict__ pML, const int TS)
{
  // K: [par][buf][32 key][256 d]  rows 512B, 16B-granule g holds chunk g^(key&7)
  // V: [par][buf][256 d][32 key]  rows  64B, granule g holds chunk g^((d>>1)&3)
  // P: [wave][32 q][32 key]       rows  64B, granule g holds chunk g^((q>>1)&3)
  __shared__ __align__(16) unsigned short smem[73728];  // 64KB K + 64KB V + 16KB P

  const int o   = blockIdx.x;
  const int cpx = gridDim.x >> 3;
  const int wg  = (o & 7) * cpx + (o >> 3);   // bijective XCD swizzle (gridDim % 8 == 0)
  const int n   = wg / (TS * 32);
  const int rem = wg - n * (TS * 32);
  const int ts  = rem >> 5;
  const int qb  = rem & 31;
  const int q0  = qb * 128;

  const int tid  = threadIdx.x;
  const int lane = tid & 63;
  const int w    = tid >> 6;   // 0..7
  const int qg   = w >> 1;     // 0..3 : q-group (also stager id within parity)
  const int par  = w & 1;      // T-parity
  const int l15  = lane & 15;
  const int lg   = lane >> 4;

  const int tpp    = 2048 / TS;          // T-range per parity
  const int ntiles = tpp >> 5;           // 32-key tiles per parity
  const int tbase  = ts * 2 * tpp + par * tpp;

  const unsigned short* kbase = Kb + ((size_t)n * 4096) * 256;
  const unsigned short* vbase = Vt + ((size_t)n * 256) * 4096;

  unsigned short* Kbuf[2] = { &smem[(par * 2 + 0) * 8192], &smem[(par * 2 + 1) * 8192] };
  unsigned short* Vbuf[2] = { &smem[32768 + (par * 2 + 0) * 8192], &smem[32768 + (par * 2 + 1) * 8192] };
  unsigned short* pw = &smem[65536 + w * 1024];

  // staging geometry: 1024 granules (16B) per tile per array, 4 waves/parity x 64 lanes x 4 its
  unsigned kOff[4], vOff[4];
  #pragma unroll
  for (int it = 0; it < 4; ++it) {
    const int gi  = it * 256 + qg * 64 + lane;
    const int key = gi >> 5, g = gi & 31;
    kOff[it] = (unsigned)(key * 256 + (g ^ (key & 7)) * 8);
    const int d = gi >> 2, gv = gi & 3;
    vOff[it] = (unsigned)(d * 4096 + (gv ^ ((d >> 1) & 3)) * 8);
  }

  #define STAGE(BUF, T0)                                                              \
    do {                                                                              \
      unsigned short* kd = Kbuf[BUF];                                                 \
      unsigned short* vd = Vbuf[BUF];                                                 \
      _Pragma("unroll")                                                               \
      for (int it = 0; it < 4; ++it)                                                  \
        __builtin_amdgcn_global_load_lds(                                             \
            (const __attribute__((address_space(1))) unsigned int*)(kbase + (size_t)(T0) * 256 + kOff[it]), \
            (__attribute__((address_space(3))) unsigned int*)&kd[(it * 256 + qg * 64) * 8], \
            16, 0, 0);                                                                \
      _Pragma("unroll")                                                               \
      for (int it = 0; it < 4; ++it)                                                  \
        __builtin_amdgcn_global_load_lds(                                             \
            (const __attribute__((address_space(1))) unsigned int*)(vbase + (size_t)(T0) + vOff[it]), \
            (__attribute__((address_space(3))) unsigned int*)&vd[(it * 256 + qg * 64) * 8], \
            16, 0, 0);                                                                \
    } while (0)

  // Q fragments: 32 q-rows per wave, rows qw + qblk*16 + l15
  const int qw = q0 + qg * 32;
  s16x8 aq[2][8];
  #pragma unroll
  for (int qk = 0; qk < 2; ++qk) {
    const size_t qoff = ((size_t)(n * 4096 + qw + qk * 16 + l15)) * 256 + lg * 8;
    #pragma unroll
    for (int kg = 0; kg < 8; ++kg)
      aq[qk][kg] = *reinterpret_cast<const s16x8*>(&Qb[qoff + kg * 32]);
  }

  f32x4 o_acc[2][16];
  #pragma unroll
  for (int qk = 0; qk < 2; ++qk)
    #pragma unroll
    for (int dt = 0; dt < 16; ++dt) o_acc[qk][dt] = {0.f, 0.f, 0.f, 0.f};
  float m[2][4], l[2][4];
  #pragma unroll
  for (int qk = 0; qk < 2; ++qk)
    #pragma unroll
    for (int j = 0; j < 4; ++j) { m[qk][j] = -1e30f; l[qk][j] = 0.0f; }

  const float c  = 0.09016844005f;   // (1/sqrt(256)) * log2(e)
  const float TH = 8.0f / c;

  STAGE(0, tbase);

  for (int i = 0; i < ntiles; ++i) {
    __builtin_amdgcn_s_barrier();
    __builtin_amdgcn_sched_barrier(0);
    if (i + 1 < ntiles) {
      STAGE((i + 1) & 1, tbase + (i + 1) * 32);
      asm volatile("s_waitcnt vmcnt(8)" ::: "memory");
    } else {
      asm volatile("s_waitcnt vmcnt(0)" ::: "memory");
    }
    __builtin_amdgcn_sched_barrier(0);
    __builtin_amdgcn_s_barrier();
    __builtin_amdgcn_sched_barrier(0);

    const unsigned short* Kt = Kbuf[i & 1];
    const unsigned short* Vw = Vbuf[i & 1];

    // QK^T: 32q x 32k
    f32x4 s[2][2];
    #pragma unroll
    for (int qk = 0; qk < 2; ++qk) { s[qk][0] = {0.f,0.f,0.f,0.f}; s[qk][1] = {0.f,0.f,0.f,0.f}; }
    __builtin_amdgcn_s_setprio(1);
    #pragma unroll
    for (int nt = 0; nt < 2; ++nt) {
      const int key = nt * 16 + l15;
      #pragma unroll
      for (int kg = 0; kg < 8; ++kg) {
        const int g = (kg * 4 + lg) ^ (key & 7);
        const s16x8 bk = *reinterpret_cast<const s16x8*>(&Kt[key * 256 + g * 8]);
        s[0][nt] = __builtin_amdgcn_mfma_f32_16x16x32_bf16(aq[0][kg], bk, s[0][nt], 0, 0, 0);
        s[1][nt] = __builtin_amdgcn_mfma_f32_16x16x32_bf16(aq[1][kg], bk, s[1][nt], 0, 0, 0);
      }
    }
    __builtin_amdgcn_s_setprio(0);

    // online softmax with defer-max (rows: q = qk*16 + lg*4 + j)
    float tmax[2][4];
    #pragma unroll
    for (int qk = 0; qk < 2; ++qk)
      #pragma unroll
      for (int j = 0; j < 4; ++j) tmax[qk][j] = fmaxf(s[qk][0][j], s[qk][1][j]);
    #pragma unroll
    for (int off = 1; off <= 8; off <<= 1)
      #pragma unroll
      for (int qk = 0; qk < 2; ++qk)
        #pragma unroll
        for (int j = 0; j < 4; ++j)
          tmax[qk][j] = fmaxf(tmax[qk][j], __shfl_xor(tmax[qk][j], off));

    bool need = false;
    #pragma unroll
    for (int qk = 0; qk < 2; ++qk)
      #pragma unroll
      for (int j = 0; j < 4; ++j) need |= (tmax[qk][j] > m[qk][j] + TH);
    if (__any((int)need)) {
      #pragma unroll
      for (int qk = 0; qk < 2; ++qk) {
        float scv[4];
        #pragma unroll
        for (int j = 0; j < 4; ++j) {
          const float mn = fmaxf(m[qk][j], tmax[qk][j]);
          scv[j] = exp2f((m[qk][j] - mn) * c);
          l[qk][j] *= scv[j];
          m[qk][j] = mn;
        }
        #pragma unroll
        for (int dt = 0; dt < 16; ++dt)
          #pragma unroll
          for (int j = 0; j < 4; ++j) o_acc[qk][dt][j] *= scv[j];
      }
    }

    float rs[2][4];
    #pragma unroll
    for (int qk = 0; qk < 2; ++qk)
      #pragma unroll
      for (int nt = 0; nt < 2; ++nt)
        #pragma unroll
        for (int j = 0; j < 4; ++j) {
          s[qk][nt][j] = exp2f((s[qk][nt][j] - m[qk][j]) * c);
          if (nt == 0) rs[qk][j] = s[qk][0][j]; else rs[qk][j] += s[qk][1][j];
        }
    #pragma unroll
    for (int off = 1; off <= 8; off <<= 1)
      #pragma unroll
      for (int qk = 0; qk < 2; ++qk)
        #pragma unroll
        for (int j = 0; j < 4; ++j) rs[qk][j] += __shfl_xor(rs[qk][j], off);
    #pragma unroll
    for (int qk = 0; qk < 2; ++qk)
      #pragma unroll
      for (int j = 0; j < 4; ++j) l[qk][j] += rs[qk][j];

    // P -> LDS bf16 (C-layout -> A-layout), swizzled
    #pragma unroll
    for (int qk = 0; qk < 2; ++qk)
      #pragma unroll
      for (int nt = 0; nt < 2; ++nt)
        #pragma unroll
        for (int j = 0; j < 4; ++j) {
          const int q   = qk * 16 + lg * 4 + j;
          const int key = nt * 16 + l15;
          const int g   = (key >> 3) ^ ((q >> 1) & 3);
          pw[q * 32 + g * 8 + (key & 7)] = f2bf(s[qk][nt][j]);
        }

    // PV: O[q][d] += P[q][key] * V[key][d]
    s16x8 ap[2];
    #pragma unroll
    for (int qk = 0; qk < 2; ++qk) {
      const int q = qk * 16 + l15;
      ap[qk] = *reinterpret_cast<const s16x8*>(&pw[q * 32 + (lg ^ ((q >> 1) & 3)) * 8]);
    }
    __builtin_amdgcn_s_setprio(1);
    #pragma unroll
    for (int dt = 0; dt < 16; ++dt) {
      const int d = dt * 16 + l15;
      const s16x8 bv = *reinterpret_cast<const s16x8*>(&Vw[d * 32 + (lg ^ ((d >> 1) & 3)) * 8]);
      o_acc[0][dt] = __builtin_amdgcn_mfma_f32_16x16x32_bf16(ap[0], bv, o_acc[0][dt], 0, 0, 0);
      o_acc[1][dt] = __builtin_amdgcn_mfma_f32_16x16x32_bf16(ap[1], bv, o_acc[1][dt], 0, 0, 0);
    }
    __builtin_amdgcn_s_setprio(0);
  }

  // ---- in-block parity merge (par1 -> LDS, par0 merges, writes unnormalized partial) ----
  __syncthreads();
  f32x4* ob  = (f32x4*)&smem[0];          // 128 KB: [qg*64+lane][32]
  float* mlb = (float*)&smem[65536];      // 16 KB : [qg*64+lane][16]
  if (par == 1) {
    f32x4* dst = ob + ((size_t)(qg * 64 + lane)) * 32;
    #pragma unroll
    for (int qk = 0; qk < 2; ++qk)
      #pragma unroll
      for (int dt = 0; dt < 16; ++dt) dst[qk * 16 + (dt ^ l15)] = o_acc[qk][dt];
    float* mld = &mlb[(qg * 64 + lane) * 16];
    #pragma unroll
    for (int qk = 0; qk < 2; ++qk)
      #pragma unroll
      for (int j = 0; j < 4; ++j) { mld[qk * 8 + j] = m[qk][j]; mld[qk * 8 + 4 + j] = l[qk][j]; }
  }
  __syncthreads();
  if (par == 0) {
    const f32x4* src = ob + ((size_t)(qg * 64 + lane)) * 32;
    const float* mld = &mlb[(qg * 64 + lane) * 16];
    float sc0[2][4], sc1[2][4];
    #pragma unroll
    for (int qk = 0; qk < 2; ++qk)
      #pragma unroll
      for (int j = 0; j < 4; ++j) {
        const float m1 = mld[qk * 8 + j], l1 = mld[qk * 8 + 4 + j];
        const float mf = fmaxf(m[qk][j], m1);
        sc0[qk][j] = exp2f((m[qk][j] - mf) * c);
        sc1[qk][j] = exp2f((m1 - mf) * c);
        const float Lt = l[qk][j] * sc0[qk][j] + l1 * sc1[qk][j];
        if (l15 == 0) {
          const size_t r = (size_t)ts * 16384 + n * 4096 + q0 + qg * 32 + qk * 16 + lg * 4 + j;
          pML[r * 2]     = mf;
          pML[r * 2 + 1] = Lt;
        }
      }
    #pragma unroll
    for (int qk = 0; qk < 2; ++qk)
      #pragma unroll
      for (int dt = 0; dt < 16; ++dt) {
        const f32x4 o1 = src[qk * 16 + (dt ^ l15)];
        #pragma unroll
        for (int j = 0; j < 4; ++j) {
          const size_t r = (size_t)ts * 16384 + n * 4096 + q0 + qg * 32 + qk * 16 + lg * 4 + j;
          pO[r * 256 + dt * 16 + l15] = o_acc[qk][dt][j] * sc0[qk][j] + o1[j] * sc1[qk][j];
        }
      }
  }
  #undef STAGE
}

// ---------------- cross-block T-split merge ----------------
__global__ __launch_bounds__(256) void merge_kernel(
    const float* __restrict__ pO, const float* __restrict__ pML,
    float* __restrict__ out, const int TS)
{
  const int idx = blockIdx.x * 256 + threadIdx.x;   // one f32x4 per thread
  const int row = idx >> 6;
  const int dp  = (idx & 63) << 2;
  const float c = 0.09016844005f;

  float M = -1e30f;
  for (int t = 0; t < TS; ++t) M = fmaxf(M, pML[((size_t)t * 16384 + row) * 2]);
  f32x4 num = {0.f, 0.f, 0.f, 0.f};
  float den = 0.f;
  for (int t = 0; t < TS; ++t) {
    const float mf = pML[((size_t)t * 16384 + row) * 2];
    const float Lt = pML[((size_t)t * 16384 + row) * 2 + 1];
    const float wt = exp2f((mf - M) * c);
    den += wt * Lt;
    const f32x4 o = *reinterpret_cast<const f32x4*>(&pO[((size_t)t * 16384 + row) * 256 + dp]);
    num[0] += wt * o[0]; num[1] += wt * o[1]; num[2] += wt * o[2]; num[3] += wt * o[3];
  }
  const float inv = 1.0f / den;
  f32x4 y = { num[0] * inv, num[1] * inv, num[2] * inv, num[3] * inv };
  *reinterpret_cast<f32x4*>(&out[(size_t)row * 256 + dp]) = y;
}

extern "C" void kernel_launch(void* const* d_in, const int* in_sizes, int n_in,
                              void* d_out, int out_size, void* d_ws, size_t ws_size,
                              hipStream_t stream) {
  const float* query = (const float*)d_in[0];
  const float* key   = (const float*)d_in[1];
  const float* value = (const float*)d_in[2];
  const float* Wq    = (const float*)d_in[3];
  const float* bq    = (const float*)d_in[4];
  const float* Wk    = (const float*)d_in[5];
  const float* bk    = (const float*)d_in[6];
  const float* Wv    = (const float*)d_in[7];
  const float* bv    = (const float*)d_in[8];
  float* out = (float*)d_out;

  unsigned short* qb = (unsigned short*)d_ws;              // [16384][256] bf16
  unsigned short* kb = qb + (size_t)16384 * 256;
  unsigned short* vt = kb + (size_t)16384 * 256;           // [4][256][4096] bf16
  const size_t base    = (size_t)3 * 16384 * 256 * 2;      // 24 MB
  const size_t poBytes = (size_t)16384 * 256 * 4;          // 16 MB per ts
  const size_t mlBytes = (size_t)16384 * 2 * 4;            // 128 KB per ts
  const int TS = (ws_size >= base + 2 * (poBytes + mlBytes)) ? 2 : 1;
  float* pO  = (float*)((char*)d_ws + base);
  float* pML = (float*)((char*)d_ws + base + (size_t)TS * poBytes);
  (void)in_sizes; (void)n_in; (void)out_size;

  proj_kernel<<<dim3(128, 2, 3), 256, 0, stream>>>(query, key, value,
                                                   Wq, bq, Wk, bk, Wv, bv,
                                                   qb, kb, vt);
  attn_kernel<<<dim3(128 * TS), 512, 0, stream>>>(qb, kb, vt, pO, pML, TS);
  merge_kernel<<<dim3(4096), 256, 0, stream>>>(pO, pML, out, TS);
}

// Round 4
// 292.792 us; speedup vs baseline: 1.9863x; 1.9863x over previous
//
#include <hip/hip_runtime.h>
#include <hip/hip_bf16.h>

typedef __attribute__((ext_vector_type(4))) float f32x4;
typedef __attribute__((ext_vector_type(8))) short s16x8;
typedef __attribute__((ext_vector_type(4))) short s16x4;

#define DEV __device__ __forceinline__

DEV unsigned short f2bf(float f) {
  union { float f; unsigned u; } v; v.f = f;
  unsigned r = v.u + 0x7FFFu + ((v.u >> 16) & 1u);
  return (unsigned short)(r >> 16);
}

// ---------------- fused QKV projection: Y = X * W^T + b (bf16 out) ----------------
__global__ __launch_bounds__(256) void proj_kernel(
    const float* __restrict__ Qx, const float* __restrict__ Kx, const float* __restrict__ Vx,
    const float* __restrict__ Wq, const float* __restrict__ bq,
    const float* __restrict__ Wk, const float* __restrict__ bk,
    const float* __restrict__ Wv, const float* __restrict__ bv,
    unsigned short* __restrict__ qb, unsigned short* __restrict__ kb,
    unsigned short* __restrict__ vt)
{
  const int z = blockIdx.z;
  const float* X = (z == 0) ? Qx : (z == 1) ? Kx : Vx;
  const float* W = (z == 0) ? Wq : (z == 1) ? Wk : Wv;
  const float* B = (z == 0) ? bq : (z == 1) ? bk : bv;
  unsigned short* Y = (z == 0) ? qb : (z == 1) ? kb : vt;
  const int out_mode = (z == 2);

  const int row0 = blockIdx.x * 128;
  const int col0 = blockIdx.y * 128;
  const int tid  = threadIdx.x;
  const int lane = tid & 63;
  const int w    = tid >> 6;
  const int wr = w >> 1, wc = w & 1;
  const int l15 = lane & 15, lg = lane >> 4;

  __shared__ unsigned short As[128][40];
  __shared__ unsigned short Bs[128][40];

  f32x4 acc[4][4];
  #pragma unroll
  for (int i = 0; i < 4; ++i)
    #pragma unroll
    for (int j = 0; j < 4; ++j) acc[i][j] = {0.f, 0.f, 0.f, 0.f};

  const int lr = tid >> 3;
  const int lc = (tid & 7) << 2;

  for (int k0 = 0; k0 < 256; k0 += 32) {
    __syncthreads();
    #pragma unroll
    for (int p = 0; p < 4; ++p) {
      const int r = p * 32 + lr;
      f32x4 a = *reinterpret_cast<const f32x4*>(&X[(size_t)(row0 + r) * 256 + k0 + lc]);
      s16x4 ha;
      ha[0] = (short)f2bf(a[0]); ha[1] = (short)f2bf(a[1]);
      ha[2] = (short)f2bf(a[2]); ha[3] = (short)f2bf(a[3]);
      *reinterpret_cast<s16x4*>(&As[r][lc]) = ha;
      f32x4 b = *reinterpret_cast<const f32x4*>(&W[(size_t)(col0 + r) * 256 + k0 + lc]);
      s16x4 hb;
      hb[0] = (short)f2bf(b[0]); hb[1] = (short)f2bf(b[1]);
      hb[2] = (short)f2bf(b[2]); hb[3] = (short)f2bf(b[3]);
      *reinterpret_cast<s16x4*>(&Bs[r][lc]) = hb;
    }
    __syncthreads();
    s16x8 af[4], bf[4];
    #pragma unroll
    for (int mi = 0; mi < 4; ++mi)
      af[mi] = *reinterpret_cast<const s16x8*>(&As[wr * 64 + mi * 16 + l15][lg * 8]);
    #pragma unroll
    for (int ni = 0; ni < 4; ++ni)
      bf[ni] = *reinterpret_cast<const s16x8*>(&Bs[wc * 64 + ni * 16 + l15][lg * 8]);
    #pragma unroll
    for (int mi = 0; mi < 4; ++mi)
      #pragma unroll
      for (int ni = 0; ni < 4; ++ni)
        acc[mi][ni] = __builtin_amdgcn_mfma_f32_16x16x32_bf16(af[mi], bf[ni], acc[mi][ni], 0, 0, 0);
  }

  #pragma unroll
  for (int ni = 0; ni < 4; ++ni) {
    const int col = col0 + wc * 64 + ni * 16 + l15;
    const float bv_ = B[col];
    #pragma unroll
    for (int mi = 0; mi < 4; ++mi)
      #pragma unroll
      for (int j = 0; j < 4; ++j) {
        const int row = row0 + wr * 64 + mi * 16 + lg * 4 + j;
        const unsigned short h = f2bf(acc[mi][ni][j] + bv_);
        if (out_mode == 0) Y[(size_t)row * 256 + col] = h;
        else Y[((size_t)((row >> 12) * 256 + col)) * 4096 + (row & 4095)] = h;
      }
  }
}

// ---------------- flash attention ----------------
// 256 blocks (1/CU), 4 waves = 2 q-groups (32 q each, q-span 64) x 2 T-parities.
// Full T-range per block (cache-friendly like round 2), direct normalized output.
__global__ __launch_bounds__(256, 1) void attn_kernel(
    const unsigned short* __restrict__ Qb,
    const unsigned short* __restrict__ Kb,
    const unsigned short* __restrict__ Vt,
    float* __restrict__ Out)
{
  // K: [par][buf][32 key][256 d] rows 512B; 16B-granule slot g holds chunk g^(key&7)  (bank bits = g&7)
  // V: [par][buf][256 d][32 key] rows 64B;  granule slot g holds chunk g^((d>>1)&3)
  // P: [wave][32 q][32 key]      rows 64B;  granule slot g holds chunk g^((q>>1)&3)
  __shared__ __align__(16) unsigned short smem[69632];  // 64KB K + 64KB V + 8KB P = 136KB

  const int o   = blockIdx.x;
  const int wg  = (o & 7) * 32 + (o >> 3);   // bijective XCD swizzle (256 blocks)
  const int n   = wg >> 6;
  const int q0  = (wg & 63) * 64;

  const int tid  = threadIdx.x;
  const int lane = tid & 63;
  const int w    = tid >> 6;   // 0..3
  const int qg   = w >> 1;     // 0..1 q-group
  const int par  = w & 1;      // T-parity
  const int l15  = lane & 15;
  const int lg   = lane >> 4;

  const unsigned short* kbase = Kb + ((size_t)n * 4096) * 256;
  const unsigned short* vbase = Vt + ((size_t)n * 256) * 4096;

  unsigned short* Kbuf[2] = { &smem[(par * 2 + 0) * 8192], &smem[(par * 2 + 1) * 8192] };
  unsigned short* Vbuf[2] = { &smem[32768 + (par * 2 + 0) * 8192], &smem[32768 + (par * 2 + 1) * 8192] };
  unsigned short* pw = &smem[65536 + w * 1024];

  // staging: 1024 granules (16B) per tile per array; 2 waves/parity x 64 lanes x 8 its
  unsigned kOff[8], vOff[8];
  #pragma unroll
  for (int it = 0; it < 8; ++it) {
    const int gi  = it * 128 + qg * 64 + lane;
    const int key = gi >> 5, g = gi & 31;
    kOff[it] = (unsigned)(key * 256 + (g ^ (key & 7)) * 8);
    const int d = gi >> 2, gv = gi & 3;
    vOff[it] = (unsigned)(d * 4096 + (gv ^ ((d >> 1) & 3)) * 8);
  }

  #define STAGE(BUF, T0)                                                              \
    do {                                                                              \
      unsigned short* kd = Kbuf[BUF];                                                 \
      unsigned short* vd = Vbuf[BUF];                                                 \
      _Pragma("unroll")                                                               \
      for (int it = 0; it < 8; ++it)                                                  \
        __builtin_amdgcn_global_load_lds(                                             \
            (const __attribute__((address_space(1))) unsigned int*)(kbase + (size_t)(T0) * 256 + kOff[it]), \
            (__attribute__((address_space(3))) unsigned int*)&kd[(it * 128 + qg * 64) * 8], \
            16, 0, 0);                                                                \
      _Pragma("unroll")                                                               \
      for (int it = 0; it < 8; ++it)                                                  \
        __builtin_amdgcn_global_load_lds(                                             \
            (const __attribute__((address_space(1))) unsigned int*)(vbase + (size_t)(T0) + vOff[it]), \
            (__attribute__((address_space(3))) unsigned int*)&vd[(it * 128 + qg * 64) * 8], \
            16, 0, 0);                                                                \
    } while (0)

  // Q fragments: 32 q-rows/wave (two 16-row fragments)
  const int qw = q0 + qg * 32;
  s16x8 aq[2][8];
  #pragma unroll
  for (int qk = 0; qk < 2; ++qk) {
    const size_t qoff = ((size_t)(n * 4096 + qw + qk * 16 + l15)) * 256 + lg * 8;
    #pragma unroll
    for (int kg = 0; kg < 8; ++kg)
      aq[qk][kg] = *reinterpret_cast<const s16x8*>(&Qb[qoff + kg * 32]);
  }

  f32x4 o_acc[2][16];
  #pragma unroll
  for (int qk = 0; qk < 2; ++qk)
    #pragma unroll
    for (int dt = 0; dt < 16; ++dt) o_acc[qk][dt] = {0.f, 0.f, 0.f, 0.f};
  float m[2][4], l[2][4];
  #pragma unroll
  for (int qk = 0; qk < 2; ++qk)
    #pragma unroll
    for (int j = 0; j < 4; ++j) { m[qk][j] = -1e30f; l[qk][j] = 0.0f; }

  const float c  = 0.09016844005f;   // (1/sqrt(256)) * log2(e)
  const float TH = 8.0f / c;

  const int tbase = par * 2048;
  STAGE(0, tbase);

  for (int i = 0; i < 64; ++i) {
    __builtin_amdgcn_s_barrier();
    __builtin_amdgcn_sched_barrier(0);
    if (i + 1 < 64) {
      STAGE((i + 1) & 1, tbase + (i + 1) * 32);
      asm volatile("s_waitcnt vmcnt(16)" ::: "memory");  // tile i landed; tile i+1 in flight
    } else {
      asm volatile("s_waitcnt vmcnt(0)" ::: "memory");
    }
    __builtin_amdgcn_sched_barrier(0);
    __builtin_amdgcn_s_barrier();
    __builtin_amdgcn_sched_barrier(0);

    const unsigned short* Kt = Kbuf[i & 1];
    const unsigned short* Vw = Vbuf[i & 1];

    // QK^T: 32q x 32k
    f32x4 s[2][2];
    #pragma unroll
    for (int qk = 0; qk < 2; ++qk) { s[qk][0] = {0.f,0.f,0.f,0.f}; s[qk][1] = {0.f,0.f,0.f,0.f}; }
    __builtin_amdgcn_s_setprio(1);
    #pragma unroll
    for (int nt = 0; nt < 2; ++nt) {
      const int key = nt * 16 + l15;
      #pragma unroll
      for (int kg = 0; kg < 8; ++kg) {
        const int g = (kg * 4 + lg) ^ (key & 7);
        const s16x8 bk = *reinterpret_cast<const s16x8*>(&Kt[key * 256 + g * 8]);
        s[0][nt] = __builtin_amdgcn_mfma_f32_16x16x32_bf16(aq[0][kg], bk, s[0][nt], 0, 0, 0);
        s[1][nt] = __builtin_amdgcn_mfma_f32_16x16x32_bf16(aq[1][kg], bk, s[1][nt], 0, 0, 0);
      }
    }
    __builtin_amdgcn_s_setprio(0);

    // online softmax with defer-max (rows: q = qk*16 + lg*4 + j)
    float tmax[2][4];
    #pragma unroll
    for (int qk = 0; qk < 2; ++qk)
      #pragma unroll
      for (int j = 0; j < 4; ++j) tmax[qk][j] = fmaxf(s[qk][0][j], s[qk][1][j]);
    #pragma unroll
    for (int off = 1; off <= 8; off <<= 1)
      #pragma unroll
      for (int qk = 0; qk < 2; ++qk)
        #pragma unroll
        for (int j = 0; j < 4; ++j)
          tmax[qk][j] = fmaxf(tmax[qk][j], __shfl_xor(tmax[qk][j], off));

    bool need = false;
    #pragma unroll
    for (int qk = 0; qk < 2; ++qk)
      #pragma unroll
      for (int j = 0; j < 4; ++j) need |= (tmax[qk][j] > m[qk][j] + TH);
    if (__any((int)need)) {
      #pragma unroll
      for (int qk = 0; qk < 2; ++qk) {
        float scv[4];
        #pragma unroll
        for (int j = 0; j < 4; ++j) {
          const float mn = fmaxf(m[qk][j], tmax[qk][j]);
          scv[j] = exp2f((m[qk][j] - mn) * c);
          l[qk][j] *= scv[j];
          m[qk][j] = mn;
        }
        #pragma unroll
        for (int dt = 0; dt < 16; ++dt)
          #pragma unroll
          for (int j = 0; j < 4; ++j) o_acc[qk][dt][j] *= scv[j];
      }
    }

    float rs[2][4];
    #pragma unroll
    for (int qk = 0; qk < 2; ++qk)
      #pragma unroll
      for (int nt = 0; nt < 2; ++nt)
        #pragma unroll
        for (int j = 0; j < 4; ++j) {
          s[qk][nt][j] = exp2f((s[qk][nt][j] - m[qk][j]) * c);
          if (nt == 0) rs[qk][j] = s[qk][0][j]; else rs[qk][j] += s[qk][1][j];
        }
    #pragma unroll
    for (int off = 1; off <= 8; off <<= 1)
      #pragma unroll
      for (int qk = 0; qk < 2; ++qk)
        #pragma unroll
        for (int j = 0; j < 4; ++j) rs[qk][j] += __shfl_xor(rs[qk][j], off);
    #pragma unroll
    for (int qk = 0; qk < 2; ++qk)
      #pragma unroll
      for (int j = 0; j < 4; ++j) l[qk][j] += rs[qk][j];

    // P -> LDS bf16 (C-layout -> A-layout), swizzled
    #pragma unroll
    for (int qk = 0; qk < 2; ++qk)
      #pragma unroll
      for (int nt = 0; nt < 2; ++nt)
        #pragma unroll
        for (int j = 0; j < 4; ++j) {
          const int q   = qk * 16 + lg * 4 + j;
          const int key = nt * 16 + l15;
          const int g   = (key >> 3) ^ ((q >> 1) & 3);
          pw[q * 32 + g * 8 + (key & 7)] = f2bf(s[qk][nt][j]);
        }

    // PV: O[q][d] += P[q][key] * V[key][d]
    s16x8 ap[2];
    #pragma unroll
    for (int qk = 0; qk < 2; ++qk) {
      const int q = qk * 16 + l15;
      ap[qk] = *reinterpret_cast<const s16x8*>(&pw[q * 32 + (lg ^ ((q >> 1) & 3)) * 8]);
    }
    __builtin_amdgcn_s_setprio(1);
    #pragma unroll
    for (int dt = 0; dt < 16; ++dt) {
      const int d = dt * 16 + l15;
      const s16x8 bv = *reinterpret_cast<const s16x8*>(&Vw[d * 32 + (lg ^ ((d >> 1) & 3)) * 8]);
      o_acc[0][dt] = __builtin_amdgcn_mfma_f32_16x16x32_bf16(ap[0], bv, o_acc[0][dt], 0, 0, 0);
      o_acc[1][dt] = __builtin_amdgcn_mfma_f32_16x16x32_bf16(ap[1], bv, o_acc[1][dt], 0, 0, 0);
    }
    __builtin_amdgcn_s_setprio(0);
  }

  // ---- in-block parity merge (par1 -> LDS, par0 merges + writes normalized out) ----
  __syncthreads();
  f32x4* ob  = (f32x4*)&smem[0];        // 64 KB: [qg*64+lane][32] f32x4
  float* mlb = (float*)&smem[32768];    // 8 KB : [qg*64+lane][16] f32
  if (par == 1) {
    f32x4* dst = ob + ((size_t)(qg * 64 + lane)) * 32;
    #pragma unroll
    for (int qk = 0; qk < 2; ++qk)
      #pragma unroll
      for (int dt = 0; dt < 16; ++dt) dst[qk * 16 + (dt ^ l15)] = o_acc[qk][dt];
    float* mld = &mlb[(qg * 64 + lane) * 16];
    #pragma unroll
    for (int qk = 0; qk < 2; ++qk)
      #pragma unroll
      for (int j = 0; j < 4; ++j) { mld[qk * 8 + j] = m[qk][j]; mld[qk * 8 + 4 + j] = l[qk][j]; }
  }
  __syncthreads();
  if (par == 0) {
    const f32x4* src = ob + ((size_t)(qg * 64 + lane)) * 32;
    const float* mld = &mlb[(qg * 64 + lane) * 16];
    float sc0[2][4], sc1[2][4], inv[2][4];
    #pragma unroll
    for (int qk = 0; qk < 2; ++qk)
      #pragma unroll
      for (int j = 0; j < 4; ++j) {
        const float m1 = mld[qk * 8 + j], l1 = mld[qk * 8 + 4 + j];
        const float mf = fmaxf(m[qk][j], m1);
        sc0[qk][j] = exp2f((m[qk][j] - mf) * c);
        sc1[qk][j] = exp2f((m1 - mf) * c);
        inv[qk][j] = 1.0f / (l[qk][j] * sc0[qk][j] + l1 * sc1[qk][j]);
      }
    #pragma unroll
    for (int qk = 0; qk < 2; ++qk)
      #pragma unroll
      for (int dt = 0; dt < 16; ++dt) {
        const f32x4 o1 = src[qk * 16 + (dt ^ l15)];
        #pragma unroll
        for (int j = 0; j < 4; ++j) {
          const size_t row = (size_t)(n * 4096 + q0 + qg * 32 + qk * 16 + lg * 4 + j);
          Out[row * 256 + dt * 16 + l15] =
              (o_acc[qk][dt][j] * sc0[qk][j] + o1[j] * sc1[qk][j]) * inv[qk][j];
        }
      }
  }
  #undef STAGE
}

extern "C" void kernel_launch(void* const* d_in, const int* in_sizes, int n_in,
                              void* d_out, int out_size, void* d_ws, size_t ws_size,
                              hipStream_t stream) {
  const float* query = (const float*)d_in[0];
  const float* key   = (const float*)d_in[1];
  const float* value = (const float*)d_in[2];
  const float* Wq    = (const float*)d_in[3];
  const float* bq    = (const float*)d_in[4];
  const float* Wk    = (const float*)d_in[5];
  const float* bk    = (const float*)d_in[6];
  const float* Wv    = (const float*)d_in[7];
  const float* bv    = (const float*)d_in[8];
  float* out = (float*)d_out;

  unsigned short* qb = (unsigned short*)d_ws;              // [16384][256] bf16
  unsigned short* kb = qb + (size_t)16384 * 256;           // [16384][256] bf16
  unsigned short* vt = kb + (size_t)16384 * 256;           // [4][256][4096] bf16
  (void)in_sizes; (void)n_in; (void)out_size; (void)ws_size;

  proj_kernel<<<dim3(128, 2, 3), 256, 0, stream>>>(query, key, value,
                                                   Wq, bq, Wk, bk, Wv, bv,
                                                   qb, kb, vt);
  attn_kernel<<<dim3(256), 256, 0, stream>>>(qb, kb, vt, out);
}